// Round 1
// baseline (1813.139 us; speedup 1.0000x reference)
//
#include <hip/hip_runtime.h>

#define B_   2
#define T_   2048
#define HID_ 1024
#define NH_  16
#define HD_  64
#define K_   1024
#define M_   (B_*T_)

// C[m,n] = sum_k A[m,k] * W[n,k]   (A: MxK row-major, W: NxK row-major)
// MODE 0: scatter to (b, h, t, d) layout (for q/k/v).  MODE 1: plain MxN.
template<int MODE>
__global__ __launch_bounds__(256)
void gemm_nt(const float* __restrict__ A, const float* __restrict__ W,
             float* __restrict__ out) {
    __shared__ float As[16][64];
    __shared__ float Bs[16][64];
    const int tid = threadIdx.x;
    const int tx = tid & 15, ty = tid >> 4;
    const int m0 = blockIdx.x * 64, n0 = blockIdx.y * 64;
    const int lrow   = tid >> 2;        // 0..63
    const int lchunk = (tid & 3) << 2;  // 0,4,8,12
    float acc[4][4] = {};
    const float* Aptr = A + (m0 + lrow) * K_ + lchunk;
    const float* Wptr = W + (n0 + lrow) * K_ + lchunk;
    for (int k0 = 0; k0 < K_; k0 += 16) {
        float4 av = *(const float4*)(Aptr + k0);
        float4 bv = *(const float4*)(Wptr + k0);
        __syncthreads();
        As[lchunk+0][lrow]=av.x; As[lchunk+1][lrow]=av.y;
        As[lchunk+2][lrow]=av.z; As[lchunk+3][lrow]=av.w;
        Bs[lchunk+0][lrow]=bv.x; Bs[lchunk+1][lrow]=bv.y;
        Bs[lchunk+2][lrow]=bv.z; Bs[lchunk+3][lrow]=bv.w;
        __syncthreads();
        #pragma unroll
        for (int k = 0; k < 16; ++k) {
            float4 a = *(const float4*)&As[k][tx<<2];
            float4 b = *(const float4*)&Bs[k][ty<<2];
            float ar[4] = {a.x,a.y,a.z,a.w};
            float br[4] = {b.x,b.y,b.z,b.w};
            #pragma unroll
            for (int i=0;i<4;++i)
                #pragma unroll
                for (int j=0;j<4;++j)
                    acc[i][j] = fmaf(ar[i], br[j], acc[i][j]);
        }
    }
    #pragma unroll
    for (int i=0;i<4;++i) {
        const int m = m0 + (tx<<2) + i;
        #pragma unroll
        for (int j=0;j<4;++j) {
            const int n = n0 + (ty<<2) + j;
            if (MODE == 0) {
                const int b = m >> 11, t = m & (T_-1);
                const int h = n >> 6,  d = n & 63;
                out[(((b*NH_+h)*T_+t)<<6) + d] = acc[i][j];
            } else {
                out[m*HID_ + n] = acc[i][j];
            }
        }
    }
}

// RoPE in-place on q and k, (b,h,t,d) layout. One thread per (bh, t, d<32) pair.
__global__ __launch_bounds__(256)
void rope_kernel(float* __restrict__ q, float* __restrict__ kbuf,
                 const float* __restrict__ cs, const float* __restrict__ sn) {
    const int idx = blockIdx.x * 256 + threadIdx.x;
    const int d  = idx & 31;
    const int t  = (idx >> 5) & (T_-1);
    const int bh = idx >> 16;
    const float c = cs[(t<<6) + d];
    const float s = sn[(t<<6) + d];
    const int base = (((bh << 11) + t) << 6);
    float q0 = q[base+d], q1 = q[base+d+32];
    q[base+d]     = fmaf(q0, c, -q1*s);
    q[base+d+32]  = fmaf(q1, c,  q0*s);
    float k0 = kbuf[base+d], k1 = kbuf[base+d+32];
    kbuf[base+d]    = fmaf(k0, c, -k1*s);
    kbuf[base+d+32] = fmaf(k1, c,  k0*s);
}

// Flash attention, fp32. One thread = one q row (q row + o accum in registers).
// Block = 256 threads = 256 consecutive q rows of one (b,h). K/V staged in LDS.
__global__ __launch_bounds__(256)
void attn_kernel(const float* __restrict__ q, const float* __restrict__ k,
                 const float* __restrict__ v, float* __restrict__ attn) {
    __shared__ float Ks[64][64];
    __shared__ float Vs[64][64];
    const int bh = blockIdx.y;
    const int qi = blockIdx.x * 256 + threadIdx.x;
    const float* qrow = q + (((size_t)bh << 11) + qi) * 64;
    float qr[64];
    #pragma unroll
    for (int i = 0; i < 16; ++i) {
        float4 t4 = *(const float4*)(qrow + 4*i);
        qr[4*i+0]=t4.x; qr[4*i+1]=t4.y; qr[4*i+2]=t4.z; qr[4*i+3]=t4.w;
    }
    float o[64];
    #pragma unroll
    for (int d = 0; d < 64; ++d) o[d] = 0.f;
    float mmax = -1e30f, lsum = 0.f;
    const int nkt = (blockIdx.x + 1) * 4;   // causal: k tiles of 64 rows
    for (int kt = 0; kt < nkt; ++kt) {
        __syncthreads();
        const float4* kb4 = (const float4*)(k + ((((size_t)bh << 11) + kt*64) << 6));
        const float4* vb4 = (const float4*)(v + ((((size_t)bh << 11) + kt*64) << 6));
        float4* Ks4 = (float4*)Ks;
        float4* Vs4 = (float4*)Vs;
        for (int f = threadIdx.x; f < 1024; f += 256) {
            Ks4[f] = kb4[f];
            Vs4[f] = vb4[f];
        }
        __syncthreads();
        const int kmax = min(64, qi - kt*64 + 1);
        for (int kr = 0; kr < kmax; ++kr) {
            float s0=0.f, s1=0.f, s2=0.f, s3=0.f;
            #pragma unroll
            for (int d = 0; d < 64; d += 4) {
                s0 = fmaf(qr[d+0], Ks[kr][d+0], s0);
                s1 = fmaf(qr[d+1], Ks[kr][d+1], s1);
                s2 = fmaf(qr[d+2], Ks[kr][d+2], s2);
                s3 = fmaf(qr[d+3], Ks[kr][d+3], s3);
            }
            const float s = ((s0+s1)+(s2+s3)) * 0.125f;
            if (s <= mmax) {
                const float p = __expf(s - mmax);
                lsum += p;
                #pragma unroll
                for (int d = 0; d < 64; ++d) o[d] = fmaf(p, Vs[kr][d], o[d]);
            } else {
                const float r = __expf(mmax - s);
                mmax = s;
                lsum = fmaf(lsum, r, 1.0f);
                #pragma unroll
                for (int d = 0; d < 64; ++d) o[d] = fmaf(o[d], r, Vs[kr][d]);
            }
        }
    }
    const float inv = 1.0f / lsum;
    const int b = bh >> 4, h = bh & 15;
    float* obase = attn + (((size_t)b << 11) + qi) * 1024 + (h << 6);
    #pragma unroll
    for (int d = 0; d < 64; d += 4) {
        float4 t4;
        t4.x = o[d+0]*inv; t4.y = o[d+1]*inv;
        t4.z = o[d+2]*inv; t4.w = o[d+3]*inv;
        *(float4*)(obase + d) = t4;
    }
}

extern "C" void kernel_launch(void* const* d_in, const int* in_sizes, int n_in,
                              void* d_out, int out_size, void* d_ws, size_t ws_size,
                              hipStream_t stream) {
    const float* x  = (const float*)d_in[0];
    const float* Wq = (const float*)d_in[1];
    const float* Wk = (const float*)d_in[2];
    const float* Wv = (const float*)d_in[3];
    const float* Wo = (const float*)d_in[4];
    const float* cs = (const float*)d_in[5];
    const float* sn = (const float*)d_in[6];
    float* out = (float*)d_out;
    float* ws = (float*)d_ws;
    float* qb = ws;                 // B*NH*T*HD = 4M floats
    float* kb = ws + 4194304;
    float* vb = ws + 8388608;
    float* ab = ws + 12582912;      // (B,T,HID) attention output

    dim3 ggrid(M_/64, HID_/64);
    gemm_nt<0><<<ggrid, 256, 0, stream>>>(x, Wq, qb);
    gemm_nt<0><<<ggrid, 256, 0, stream>>>(x, Wk, kb);
    gemm_nt<0><<<ggrid, 256, 0, stream>>>(x, Wv, vb);

    rope_kernel<<<(B_*NH_*T_*32)/256, 256, 0, stream>>>(qb, kb, cs, sn);

    attn_kernel<<<dim3(T_/256, B_*NH_), 256, 0, stream>>>(qb, kb, vb, ab);

    gemm_nt<1><<<ggrid, 256, 0, stream>>>(ab, Wo, out);
}

// Round 2
// 243.565 us; speedup vs baseline: 7.4442x; 7.4442x over previous
//
#include <hip/hip_runtime.h>
#include <hip/hip_bf16.h>

#define B_   2
#define T_   2048
#define HID_ 1024
#define NH_  16
#define HD_  64
#define K_   1024
#define M_   (B_*T_)

typedef __attribute__((ext_vector_type(8))) short  bf16x8;
typedef __attribute__((ext_vector_type(4))) float  f32x4;
typedef __attribute__((ext_vector_type(4))) unsigned int u32x4;
typedef __attribute__((ext_vector_type(4))) unsigned short u16x4;

__device__ inline unsigned short f2bf(float f) {
    __hip_bfloat16 h = __float2bfloat16(f);
    return __builtin_bit_cast(unsigned short, h);
}
__device__ inline float bf2f(unsigned short u) {
    return __builtin_bit_cast(float, (unsigned int)u << 16);
}
__device__ inline unsigned int pk2(float a, float b) {
    return (unsigned int)f2bf(a) | ((unsigned int)f2bf(b) << 16);
}

// ---------------- fp32 -> bf16 cast ----------------
__global__ __launch_bounds__(256)
void cast_bf16_kernel(const float* __restrict__ in, unsigned short* __restrict__ out, int n4) {
    int i = blockIdx.x * 256 + threadIdx.x;
    if (i >= n4) return;
    float4 f = ((const float4*)in)[i];
    u16x4 o = { f2bf(f.x), f2bf(f.y), f2bf(f.z), f2bf(f.w) };
    ((u16x4*)out)[i] = o;
}

// ---------------- bf16 GEMM-NT: C[m,n] = sum_k A[m,k]*W[n,k] ----------------
// 128x128 tile, BK=64, 4 waves each computing 64x64 (4x4 frags of 16x16x32).
// MODE 0: scatter bf16 to (b,h,t,d). MODE 1: fp32 MxN.
template<int MODE>
__global__ __launch_bounds__(256)
void gemm_bf16(const unsigned short* __restrict__ A, const unsigned short* __restrict__ W,
               void* __restrict__ outp) {
    __shared__ unsigned short As[128*64];
    __shared__ unsigned short Bs[128*64];
    const int tid = threadIdx.x;
    const int w = tid >> 6, lane = tid & 63;
    const int u = lane >> 4, c = lane & 15;
    const int bm = blockIdx.x * 128, bn = blockIdx.y * 128;
    const int wm = (w & 1) * 64, wn = (w >> 1) * 64;
    f32x4 acc[4][4] = {};
    const int srow = tid >> 3;          // 0..31
    const int scol = (tid & 7) << 3;    // 0..56, K offset of this thread's 8 elems
    const unsigned short* Ap = A + (size_t)(bm + srow) * K_ + scol;
    const unsigned short* Wp = W + (size_t)(bn + srow) * K_ + scol;
    bf16x8 ra[4], rb[4];
    #pragma unroll
    for (int i = 0; i < 4; ++i) {
        ra[i] = *(const bf16x8*)(Ap + (size_t)i * 32 * K_);
        rb[i] = *(const bf16x8*)(Wp + (size_t)i * 32 * K_);
    }
    for (int k0 = 0; k0 < K_; k0 += 64) {
        __syncthreads();
        #pragma unroll
        for (int i = 0; i < 4; ++i) {
            const int row = i * 32 + srow;
            const int sc = (scol * 2) ^ ((row & 7) << 4);   // swizzled byte col
            *(bf16x8*)((char*)As + row * 128 + sc) = ra[i];
            *(bf16x8*)((char*)Bs + row * 128 + sc) = rb[i];
        }
        __syncthreads();
        if (k0 < K_ - 64) {
            #pragma unroll
            for (int i = 0; i < 4; ++i) {
                ra[i] = *(const bf16x8*)(Ap + k0 + 64 + (size_t)i * 32 * K_);
                rb[i] = *(const bf16x8*)(Wp + k0 + 64 + (size_t)i * 32 * K_);
            }
        }
        #pragma unroll
        for (int kk = 0; kk < 2; ++kk) {
            bf16x8 af[4], bfr[4];
            #pragma unroll
            for (int mi = 0; mi < 4; ++mi) {
                const int row = wm + mi * 16 + c;
                const int sc = (kk * 64 + u * 16) ^ ((row & 7) << 4);
                af[mi] = *(const bf16x8*)((char*)As + row * 128 + sc);
            }
            #pragma unroll
            for (int ni = 0; ni < 4; ++ni) {
                const int row = wn + ni * 16 + c;
                const int sc = (kk * 64 + u * 16) ^ ((row & 7) << 4);
                bfr[ni] = *(const bf16x8*)((char*)Bs + row * 128 + sc);
            }
            #pragma unroll
            for (int mi = 0; mi < 4; ++mi)
                #pragma unroll
                for (int ni = 0; ni < 4; ++ni)
                    acc[mi][ni] = __builtin_amdgcn_mfma_f32_16x16x32_bf16(
                        af[mi], bfr[ni], acc[mi][ni], 0, 0, 0);
        }
    }
    #pragma unroll
    for (int mi = 0; mi < 4; ++mi) {
        #pragma unroll
        for (int ni = 0; ni < 4; ++ni) {
            #pragma unroll
            for (int r = 0; r < 4; ++r) {
                const int mg = bm + wm + mi * 16 + 4 * u + r;
                const int ng = bn + wn + ni * 16 + c;
                const float val = acc[mi][ni][r];
                if (MODE == 0) {
                    unsigned short* o = (unsigned short*)outp;
                    const int b = mg >> 11, t = mg & (T_-1);
                    const int hh = ng >> 6, d = ng & 63;
                    o[((size_t)((b * NH_ + hh) * T_ + t)) * 64 + d] = f2bf(val);
                } else {
                    ((float*)outp)[(size_t)mg * HID_ + ng] = val;
                }
            }
        }
    }
}

// ---------------- RoPE on bf16 q/k (q also scaled by 1/8) ----------------
__global__ __launch_bounds__(256)
void rope_bf16(unsigned short* __restrict__ qb, unsigned short* __restrict__ kb,
               const float* __restrict__ cs, const float* __restrict__ sn) {
    const int idx = blockIdx.x * 256 + threadIdx.x;   // 32*2048*8 total
    const int d4 = (idx & 7) * 4;
    const int t  = (idx >> 3) & (T_-1);
    const int bh = idx >> 14;
    const size_t base = ((size_t)(bh * T_) + t) * 64;
    float4 cv = *(const float4*)(cs + t * 64 + d4);
    float4 sv = *(const float4*)(sn + t * 64 + d4);
    float cc[4] = {cv.x, cv.y, cv.z, cv.w};
    float ss[4] = {sv.x, sv.y, sv.z, sv.w};
    u16x4 ql = *(u16x4*)(qb + base + d4);
    u16x4 qh = *(u16x4*)(qb + base + d4 + 32);
    u16x4 kl = *(u16x4*)(kb + base + d4);
    u16x4 kh = *(u16x4*)(kb + base + d4 + 32);
    #pragma unroll
    for (int j = 0; j < 4; ++j) {
        float q0 = bf2f(ql[j]), q1 = bf2f(qh[j]);
        ql[j] = f2bf((q0 * cc[j] - q1 * ss[j]) * 0.125f);
        qh[j] = f2bf((q1 * cc[j] + q0 * ss[j]) * 0.125f);
        float k0 = bf2f(kl[j]), k1 = bf2f(kh[j]);
        kl[j] = f2bf(k0 * cc[j] - k1 * ss[j]);
        kh[j] = f2bf(k1 * cc[j] + k0 * ss[j]);
    }
    *(u16x4*)(qb + base + d4) = ql;
    *(u16x4*)(qb + base + d4 + 32) = qh;
    *(u16x4*)(kb + base + d4) = kl;
    *(u16x4*)(kb + base + d4 + 32) = kh;
}

// ---------------- MFMA flash attention ----------------
// Block: 4 waves x 16 q-rows = 64 q rows of one (b,h). KV tiles of 32.
// Swapped QK^T: S^T = mfma(K, Q) -> lane owns q-row = lane&15.
__global__ __launch_bounds__(256)
void attn_mfma(const unsigned short* __restrict__ q, const unsigned short* __restrict__ k,
               const unsigned short* __restrict__ v, unsigned short* __restrict__ ab) {
    __shared__ unsigned short Ks[32 * 72];   // padded: stride 72 elems (144B)
    __shared__ unsigned short VT[64 * 40];   // V transposed [d][k], stride 40 (80B)
    const int tid = threadIdx.x;
    const int w = tid >> 6, lane = tid & 63;
    const int u = lane >> 4, c = lane & 15;
    const int bh = blockIdx.y, b = bh >> 4, h = bh & 15;
    const int q0blk = blockIdx.x * 64;
    const int q0w = q0blk + w * 16;
    const unsigned short* qrow = q + ((size_t)(bh * T_) + q0w + c) * 64;
    bf16x8 aq0 = *(const bf16x8*)(qrow + 8 * u);
    bf16x8 aq1 = *(const bf16x8*)(qrow + 32 + 8 * u);
    f32x4 O[4] = {};
    float m = -INFINITY, l = 0.f;
    const int qg = q0w + c;                 // this lane's q row (global)
    const int ntiles = (q0blk + 64) >> 5;
    for (int kt = 0; kt < ntiles; ++kt) {
        const int kvs = kt << 5;
        __syncthreads();
        {
            const int r = tid >> 3, c8 = (tid & 7) << 3;
            const size_t gbase = ((size_t)(bh * T_) + kvs + r) * 64 + c8;
            bf16x8 kv_ = *(const bf16x8*)(k + gbase);
            bf16x8 vv  = *(const bf16x8*)(v + gbase);
            *(bf16x8*)&Ks[r * 72 + c8] = kv_;
            #pragma unroll
            for (int j = 0; j < 8; ++j)
                VT[(c8 + j) * 40 + r] = (unsigned short)vv[j];
        }
        __syncthreads();
        // S^T = K_tile (32x64) @ Q^T (64x16), two 16-row m-tiles
        f32x4 st[2];
        #pragma unroll
        for (int mt = 0; mt < 2; ++mt) {
            bf16x8 kf0 = *(const bf16x8*)&Ks[(mt * 16 + c) * 72 + 8 * u];
            bf16x8 kf1 = *(const bf16x8*)&Ks[(mt * 16 + c) * 72 + 32 + 8 * u];
            f32x4 z = {};
            z = __builtin_amdgcn_mfma_f32_16x16x32_bf16(kf0, aq0, z, 0, 0, 0);
            z = __builtin_amdgcn_mfma_f32_16x16x32_bf16(kf1, aq1, z, 0, 0, 0);
            st[mt] = z;
        }
        // causal mask + online softmax (per-lane q-row)
        float p[2][4];
        float tmax = -INFINITY;
        #pragma unroll
        for (int mt = 0; mt < 2; ++mt)
            #pragma unroll
            for (int r = 0; r < 4; ++r) {
                const int kg = kvs + mt * 16 + 4 * u + r;
                float s = st[mt][r];
                s = (kg <= qg) ? s : -INFINITY;
                p[mt][r] = s;
                tmax = fmaxf(tmax, s);
            }
        tmax = fmaxf(tmax, __shfl_xor(tmax, 16));
        tmax = fmaxf(tmax, __shfl_xor(tmax, 32));
        const float mn = fmaxf(m, tmax);
        const float f = __expf(m - mn);
        float psum = 0.f;
        #pragma unroll
        for (int mt = 0; mt < 2; ++mt)
            #pragma unroll
            for (int r = 0; r < 4; ++r) {
                p[mt][r] = __expf(p[mt][r] - mn);
                psum += p[mt][r];
            }
        psum += __shfl_xor(psum, 16);
        psum += __shfl_xor(psum, 32);
        l = l * f + psum;
        m = mn;
        #pragma unroll
        for (int r = 0; r < 4; ++r) {
            const float fr = __shfl(f, 4 * u + r);
            O[0][r] *= fr; O[1][r] *= fr; O[2][r] *= fr; O[3][r] *= fr;
        }
        // redistribute P (S^T layout) to PV A-frag layout via shuffles
        unsigned int P0a = pk2(p[0][0], p[0][1]), P0b = pk2(p[0][2], p[0][3]);
        unsigned int P1a = pk2(p[1][0], p[1][1]), P1b = pk2(p[1][2], p[1][3]);
        const int slo = c + ((u & 1) << 5);
        const int shi = slo + 16;
        unsigned int w0a = __shfl(P0a, slo), w0b = __shfl(P0b, slo);
        unsigned int w1a = __shfl(P1a, slo), w1b = __shfl(P1b, slo);
        unsigned int x0a = __shfl(P0a, shi), x0b = __shfl(P0b, shi);
        unsigned int x1a = __shfl(P1a, shi), x1b = __shfl(P1b, shi);
        const bool hi = (u >> 1) != 0;
        u32x4 pw = { hi ? w1a : w0a, hi ? w1b : w0b,
                     hi ? x1a : x0a, hi ? x1b : x0b };
        bf16x8 pa = __builtin_bit_cast(bf16x8, pw);
        // O += P @ V  (V from transposed LDS)
        #pragma unroll
        for (int ch = 0; ch < 4; ++ch) {
            bf16x8 vf = *(const bf16x8*)&VT[(ch * 16 + c) * 40 + 8 * u];
            O[ch] = __builtin_amdgcn_mfma_f32_16x16x32_bf16(pa, vf, O[ch], 0, 0, 0);
        }
    }
    #pragma unroll
    for (int r = 0; r < 4; ++r) {
        const float li = __shfl(l, 4 * u + r);
        const float inv = 1.0f / li;
        unsigned short* orow = ab + ((size_t)(b * T_) + q0w + 4 * u + r) * HID_ + h * 64 + c;
        orow[0]  = f2bf(O[0][r] * inv);
        orow[16] = f2bf(O[1][r] * inv);
        orow[32] = f2bf(O[2][r] * inv);
        orow[48] = f2bf(O[3][r] * inv);
    }
}

extern "C" void kernel_launch(void* const* d_in, const int* in_sizes, int n_in,
                              void* d_out, int out_size, void* d_ws, size_t ws_size,
                              hipStream_t stream) {
    const float* x  = (const float*)d_in[0];
    const float* Wq = (const float*)d_in[1];
    const float* Wk = (const float*)d_in[2];
    const float* Wv = (const float*)d_in[3];
    const float* Wo = (const float*)d_in[4];
    const float* cs = (const float*)d_in[5];
    const float* sn = (const float*)d_in[6];
    float* out = (float*)d_out;
    char* wsb = (char*)d_ws;
    unsigned short* xb  = (unsigned short*)(wsb);
    unsigned short* wqb = (unsigned short*)(wsb + (8u  << 20));
    unsigned short* wkb = (unsigned short*)(wsb + (10u << 20));
    unsigned short* wvb = (unsigned short*)(wsb + (12u << 20));
    unsigned short* wob = (unsigned short*)(wsb + (14u << 20));
    unsigned short* qb  = (unsigned short*)(wsb + (16u << 20));
    unsigned short* kb  = (unsigned short*)(wsb + (24u << 20));
    unsigned short* vb  = (unsigned short*)(wsb + (32u << 20));
    unsigned short* ab  = (unsigned short*)(wsb + (40u << 20));

    cast_bf16_kernel<<<4096, 256, 0, stream>>>(x,  xb,  M_ * HID_ / 4);
    cast_bf16_kernel<<<1024, 256, 0, stream>>>(Wq, wqb, HID_ * HID_ / 4);
    cast_bf16_kernel<<<1024, 256, 0, stream>>>(Wk, wkb, HID_ * HID_ / 4);
    cast_bf16_kernel<<<1024, 256, 0, stream>>>(Wv, wvb, HID_ * HID_ / 4);
    cast_bf16_kernel<<<1024, 256, 0, stream>>>(Wo, wob, HID_ * HID_ / 4);

    dim3 ggrid(M_ / 128, HID_ / 128);
    gemm_bf16<0><<<ggrid, 256, 0, stream>>>(xb, wqb, qb);
    gemm_bf16<0><<<ggrid, 256, 0, stream>>>(xb, wkb, kb);
    gemm_bf16<0><<<ggrid, 256, 0, stream>>>(xb, wvb, vb);

    rope_bf16<<<(B_ * NH_ * T_ * 8) / 256, 256, 0, stream>>>(qb, kb, cs, sn);

    attn_mfma<<<dim3(T_ / 64, B_ * NH_), 256, 0, stream>>>(qb, kb, vb, ab);

    gemm_bf16<1><<<ggrid, 256, 0, stream>>>(ab, wob, out);
}

// Round 3
// 190.986 us; speedup vs baseline: 9.4936x; 1.2753x over previous
//
#include <hip/hip_runtime.h>
#include <hip/hip_bf16.h>

#define B_   2
#define T_   2048
#define HID_ 1024
#define NH_  16
#define HD_  64
#define K_   1024
#define M_   (B_*T_)

typedef __attribute__((ext_vector_type(8))) short  bf16x8;
typedef __attribute__((ext_vector_type(4))) float  f32x4;
typedef __attribute__((ext_vector_type(4))) unsigned int u32x4;

__device__ inline unsigned short f2bf(float f) {
    __hip_bfloat16 h = __float2bfloat16(f);
    return __builtin_bit_cast(unsigned short, h);
}
__device__ inline unsigned int pk2(float a, float b) {
    return (unsigned int)f2bf(a) | ((unsigned int)f2bf(b) << 16);
}
__device__ inline bf16x8 cvt8(float4 a, float4 b) {
    bf16x8 r;
    r[0]=(short)f2bf(a.x); r[1]=(short)f2bf(a.y); r[2]=(short)f2bf(a.z); r[3]=(short)f2bf(a.w);
    r[4]=(short)f2bf(b.x); r[5]=(short)f2bf(b.y); r[6]=(short)f2bf(b.z); r[7]=(short)f2bf(b.w);
    return r;
}

// ---------------- GEMM-NT ----------------
// TYPE 0: fused QKV. A = x (fp32, MxK), W = Wq/Wk/Wv by n-section (fp32, converted
//         in staging). Epilogue: Q -> RoPE*0.125 -> (b,h,t,d) bf16; K -> RoPE ->
//         (b,h,t,d) bf16; V -> transposed (b,h,d,t) bf16.
// TYPE 1: A = ab (bf16), W = Wo (fp32), out = fp32 MxN.
template<int TYPE>
__global__ __launch_bounds__(256)
void gemm_k(const void* __restrict__ Av, const float* __restrict__ W0,
            const float* __restrict__ W1, const float* __restrict__ W2,
            const float* __restrict__ cs, const float* __restrict__ sn,
            unsigned short* __restrict__ qb, unsigned short* __restrict__ kb,
            unsigned short* __restrict__ vtb, float* __restrict__ fout) {
    __shared__ unsigned short As[128*64];
    __shared__ unsigned short Bs[128*64];
    const int tid = threadIdx.x;
    const int w = tid >> 6, lane = tid & 63;
    const int u = lane >> 4, c = lane & 15;
    const int bm = blockIdx.x * 128, bn = blockIdx.y * 128;
    const int wm = (w & 1) * 64, wn = (w >> 1) * 64;
    const int srow = tid >> 3, scol = (tid & 7) << 3;

    const float* Wsec;
    int wrowbase;
    if constexpr (TYPE == 0) {
        const int sec = bn >> 10;
        Wsec = (sec == 0) ? W0 : ((sec == 1) ? W1 : W2);
        wrowbase = bn & 1023;
    } else {
        Wsec = W0;
        wrowbase = bn;
    }
    const float* Wp = Wsec + (size_t)(wrowbase + srow) * K_ + scol;
    const float* Af = (const float*)Av;
    const unsigned short* Ab = (const unsigned short*)Av;

    f32x4 acc[4][4] = {};
    float4 rwf[4][2];
    float4 raf[4][2];
    bf16x8 rab[4];

    auto loadin = [&](int k0) {
        #pragma unroll
        for (int i = 0; i < 4; ++i) {
            if constexpr (TYPE == 0) {
                raf[i][0] = *(const float4*)(Af + (size_t)(bm + srow + i*32) * K_ + scol + k0);
                raf[i][1] = *(const float4*)(Af + (size_t)(bm + srow + i*32) * K_ + scol + k0 + 4);
            } else {
                rab[i] = *(const bf16x8*)(Ab + (size_t)(bm + srow + i*32) * K_ + scol + k0);
            }
            rwf[i][0] = *(const float4*)(Wp + (size_t)i * 32 * K_ + k0);
            rwf[i][1] = *(const float4*)(Wp + (size_t)i * 32 * K_ + k0 + 4);
        }
    };
    loadin(0);

    for (int k0 = 0; k0 < K_; k0 += 64) {
        __syncthreads();
        #pragma unroll
        for (int i = 0; i < 4; ++i) {
            const int row = i * 32 + srow;
            const int sc = (scol * 2) ^ ((row & 7) << 4);
            bf16x8 a8;
            if constexpr (TYPE == 0) a8 = cvt8(raf[i][0], raf[i][1]);
            else                     a8 = rab[i];
            *(bf16x8*)((char*)As + row * 128 + sc) = a8;
            *(bf16x8*)((char*)Bs + row * 128 + sc) = cvt8(rwf[i][0], rwf[i][1]);
        }
        __syncthreads();
        if (k0 < K_ - 64) loadin(k0 + 64);
        #pragma unroll
        for (int kk = 0; kk < 2; ++kk) {
            bf16x8 af[4], bfr[4];
            #pragma unroll
            for (int mi = 0; mi < 4; ++mi) {
                const int row = wm + mi * 16 + c;
                const int sc = (kk * 64 + u * 16) ^ ((row & 7) << 4);
                af[mi] = *(const bf16x8*)((char*)As + row * 128 + sc);
            }
            #pragma unroll
            for (int ni = 0; ni < 4; ++ni) {
                const int row = wn + ni * 16 + c;
                const int sc = (kk * 64 + u * 16) ^ ((row & 7) << 4);
                bfr[ni] = *(const bf16x8*)((char*)Bs + row * 128 + sc);
            }
            #pragma unroll
            for (int mi = 0; mi < 4; ++mi)
                #pragma unroll
                for (int ni = 0; ni < 4; ++ni)
                    acc[mi][ni] = __builtin_amdgcn_mfma_f32_16x16x32_bf16(
                        af[mi], bfr[ni], acc[mi][ni], 0, 0, 0);
        }
    }

    if constexpr (TYPE == 1) {
        #pragma unroll
        for (int mi = 0; mi < 4; ++mi)
            #pragma unroll
            for (int ni = 0; ni < 4; ++ni)
                #pragma unroll
                for (int r = 0; r < 4; ++r)
                    fout[(size_t)(bm + wm + 16*mi + 4*u + r) * HID_ + (bn + wn + 16*ni + c)] =
                        acc[mi][ni][r];
    } else {
        const int sec = bn >> 10;
        const int h = ((bn + wn) & 1023) >> 6;
        if (sec == 2) {
            // V transposed: (b,h,d,t)
            #pragma unroll
            for (int mi = 0; mi < 4; ++mi)
                #pragma unroll
                for (int r = 0; r < 4; ++r) {
                    const int mg = bm + wm + 16*mi + 4*u + r;
                    const int bb = mg >> 11, t = mg & 2047;
                    #pragma unroll
                    for (int ni = 0; ni < 4; ++ni)
                        vtb[((size_t)(bb*16 + h) * 64 + 16*ni + c) * 2048 + t] =
                            f2bf(acc[mi][ni][r]);
                }
        } else {
            unsigned short* ob = sec ? kb : qb;
            const float qsc = sec ? 1.0f : 0.125f;
            #pragma unroll
            for (int mi = 0; mi < 4; ++mi)
                #pragma unroll
                for (int r = 0; r < 4; ++r) {
                    const int mg = bm + wm + 16*mi + 4*u + r;
                    const int bb = mg >> 11, t = mg & 2047;
                    const size_t base = ((size_t)(bb*16 + h) * 2048 + t) * 64;
                    #pragma unroll
                    for (int ni = 0; ni < 2; ++ni) {
                        const int dlo = 16*ni + c;
                        const float cv = cs[t*64 + dlo], sv = sn[t*64 + dlo];
                        const float Aa = acc[mi][ni][r], Bb = acc[mi][ni+2][r];
                        ob[base + dlo]      = f2bf((Aa*cv - Bb*sv) * qsc);
                        ob[base + dlo + 32] = f2bf((Bb*cv + Aa*sv) * qsc);
                    }
                }
        }
    }
}

// ---------------- LDS-free, barrier-free MFMA flash attention ----------------
// 4 waves x 32 q-rows = 128 q rows per block; KV tiles of 64 (4 x 16-row mt).
// K frags + V^T frags loaded directly from global (L2-resident per (b,h)).
__global__ __launch_bounds__(256)
void attn2(const unsigned short* __restrict__ q, const unsigned short* __restrict__ k,
           const unsigned short* __restrict__ vt, unsigned short* __restrict__ ab) {
    const int tid = threadIdx.x, w = tid >> 6, lane = tid & 63;
    const int u = lane >> 4, c = lane & 15;
    const int bh = blockIdx.y, b = bh >> 4, h = bh & 15;
    const int qblk = gridDim.x - 1 - blockIdx.x;      // heavy blocks first
    const int q0w = qblk * 128 + w * 32;
    const unsigned short* qp = q  + (size_t)bh * T_ * 64;
    const unsigned short* kp = k  + (size_t)bh * T_ * 64;
    const unsigned short* vp = vt + (size_t)bh * 64 * T_;

    bf16x8 aq[2][2];
    #pragma unroll
    for (int qs = 0; qs < 2; ++qs)
        #pragma unroll
        for (int ks = 0; ks < 2; ++ks)
            aq[qs][ks] = *(const bf16x8*)(qp + (size_t)(q0w + 16*qs + c) * 64 + 32*ks + 8*u);

    f32x4 O[2][4] = {};
    float mrun[2] = {-1e30f, -1e30f}, lrun[2] = {0.f, 0.f};
    const int ntiles = (q0w + 32 + 63) >> 6;

    for (int kt = 0; kt < ntiles; ++kt) {
        const int kvs = kt << 6;
        const int rem = q0w + 32 - kvs;
        const int mtmax = (rem >= 64) ? 4 : ((rem + 15) >> 4);   // 2 or 4
        const bool needmask = (kvs + 64 > q0w);

        bf16x8 kf[4][2], av[4][2];
        #pragma unroll
        for (int mt = 0; mt < 4; ++mt)
            if (mt < mtmax)
                #pragma unroll
                for (int ks = 0; ks < 2; ++ks)
                    kf[mt][ks] = *(const bf16x8*)(kp + (size_t)(kvs + 16*mt + c) * 64 + 32*ks + 8*u);
        #pragma unroll
        for (int ch = 0; ch < 4; ++ch)
            #pragma unroll
            for (int ks = 0; ks < 2; ++ks)
                if (2*ks < mtmax)
                    av[ch][ks] = *(const bf16x8*)(vp + (size_t)(16*ch + c) * T_ + kvs + 32*ks + 8*u);

        #pragma unroll
        for (int qs = 0; qs < 2; ++qs) {
            f32x4 st[4] = {};
            #pragma unroll
            for (int mt = 0; mt < 4; ++mt)
                if (mt < mtmax) {
                    f32x4 z = {};
                    z = __builtin_amdgcn_mfma_f32_16x16x32_bf16(kf[mt][0], aq[qs][0], z, 0, 0, 0);
                    z = __builtin_amdgcn_mfma_f32_16x16x32_bf16(kf[mt][1], aq[qs][1], z, 0, 0, 0);
                    st[mt] = z;
                }
            const int qg = q0w + 16*qs + c;
            float p[4][4];
            float tmax = -1e30f;
            #pragma unroll
            for (int mt = 0; mt < 4; ++mt)
                #pragma unroll
                for (int r = 0; r < 4; ++r) {
                    float s = (mt < mtmax) ? st[mt][r] : -1e30f;
                    if (needmask && (kvs + 16*mt + 4*u + r > qg)) s = -1e30f;
                    p[mt][r] = s;
                    tmax = fmaxf(tmax, s);
                }
            tmax = fmaxf(tmax, __shfl_xor(tmax, 16));
            tmax = fmaxf(tmax, __shfl_xor(tmax, 32));
            const float mn = fmaxf(mrun[qs], tmax);
            const float f = __expf(mrun[qs] - mn);
            mrun[qs] = mn;
            float psum = 0.f;
            #pragma unroll
            for (int mt = 0; mt < 4; ++mt)
                #pragma unroll
                for (int r = 0; r < 4; ++r) {
                    if (mt < mtmax) {
                        const float e = __expf(p[mt][r] - mn);
                        p[mt][r] = e; psum += e;
                    } else p[mt][r] = 0.f;
                }
            psum += __shfl_xor(psum, 16);
            psum += __shfl_xor(psum, 32);
            lrun[qs] = lrun[qs] * f + psum;
            #pragma unroll
            for (int r = 0; r < 4; ++r) {
                const float fr = __shfl(f, 4*u + r);
                #pragma unroll
                for (int ch = 0; ch < 4; ++ch) O[qs][ch][r] *= fr;
            }
            unsigned int wd[4][2];
            #pragma unroll
            for (int mt = 0; mt < 4; ++mt) {
                wd[mt][0] = pk2(p[mt][0], p[mt][1]);
                wd[mt][1] = pk2(p[mt][2], p[mt][3]);
            }
            const int slo = c + 32 * (u & 1);
            const int shi = slo + 16;
            #pragma unroll
            for (int ks = 0; ks < 2; ++ks)
                if (2*ks < mtmax) {
                    const unsigned int A0 = __shfl(wd[2*ks][0], slo),  B0 = __shfl(wd[2*ks+1][0], slo);
                    const unsigned int A1 = __shfl(wd[2*ks][1], slo),  B1 = __shfl(wd[2*ks+1][1], slo);
                    const unsigned int A2 = __shfl(wd[2*ks][0], shi),  B2 = __shfl(wd[2*ks+1][0], shi);
                    const unsigned int A3 = __shfl(wd[2*ks][1], shi),  B3 = __shfl(wd[2*ks+1][1], shi);
                    const bool hi = (u >> 1) != 0;
                    u32x4 pw = { hi ? B0 : A0, hi ? B1 : A1, hi ? B2 : A2, hi ? B3 : A3 };
                    bf16x8 pa = __builtin_bit_cast(bf16x8, pw);
                    #pragma unroll
                    for (int ch = 0; ch < 4; ++ch)
                        O[qs][ch] = __builtin_amdgcn_mfma_f32_16x16x32_bf16(
                            pa, av[ch][ks], O[qs][ch], 0, 0, 0);
                }
        }
    }

    #pragma unroll
    for (int qs = 0; qs < 2; ++qs)
        #pragma unroll
        for (int r = 0; r < 4; ++r) {
            const float li = __shfl(lrun[qs], 4*u + r);
            const float inv = 1.0f / li;
            unsigned short* orow = ab + ((size_t)(b * T_) + q0w + 16*qs + 4*u + r) * HID_ + h * 64 + c;
            #pragma unroll
            for (int ch = 0; ch < 4; ++ch)
                orow[16*ch] = f2bf(O[qs][ch][r] * inv);
        }
}

extern "C" void kernel_launch(void* const* d_in, const int* in_sizes, int n_in,
                              void* d_out, int out_size, void* d_ws, size_t ws_size,
                              hipStream_t stream) {
    const float* x  = (const float*)d_in[0];
    const float* Wq = (const float*)d_in[1];
    const float* Wk = (const float*)d_in[2];
    const float* Wv = (const float*)d_in[3];
    const float* Wo = (const float*)d_in[4];
    const float* cs = (const float*)d_in[5];
    const float* sn = (const float*)d_in[6];
    char* wsb = (char*)d_ws;
    unsigned short* qb  = (unsigned short*)(wsb);
    unsigned short* kb  = (unsigned short*)(wsb + 8388608);
    unsigned short* vtb = (unsigned short*)(wsb + 16777216);
    unsigned short* ab  = (unsigned short*)(wsb + 25165824);

    gemm_k<0><<<dim3(M_/128, 3072/128), 256, 0, stream>>>(
        x, Wq, Wk, Wv, cs, sn, qb, kb, vtb, nullptr);
    attn2<<<dim3(T_/128, B_*NH_), 256, 0, stream>>>(qb, kb, vtb, ab);
    gemm_k<1><<<dim3(M_/128, HID_/128), 256, 0, stream>>>(
        ab, Wo, nullptr, nullptr, nullptr, nullptr,
        nullptr, nullptr, nullptr, (float*)d_out);
}

// Round 5
// 189.652 us; speedup vs baseline: 9.5603x; 1.0070x over previous
//
#include <hip/hip_runtime.h>
#include <hip/hip_bf16.h>

#define B_   2
#define T_   2048
#define HID_ 1024
#define NH_  16
#define HD_  64
#define K_   1024
#define M_   (B_*T_)

typedef __attribute__((ext_vector_type(8)))  short bf16x8;
typedef __attribute__((ext_vector_type(4)))  float f32x4;
typedef __attribute__((ext_vector_type(16))) float f32x16;
typedef __attribute__((ext_vector_type(4)))  unsigned int u32x4;

__device__ inline unsigned short f2bf(float f) {
    __hip_bfloat16 h = __float2bfloat16(f);
    return __builtin_bit_cast(unsigned short, h);
}
__device__ inline unsigned int pk2(float a, float b) {
    return (unsigned int)f2bf(a) | ((unsigned int)f2bf(b) << 16);
}
__device__ inline bf16x8 cvt8(float4 a, float4 b) {
    bf16x8 r;
    r[0]=(short)f2bf(a.x); r[1]=(short)f2bf(a.y); r[2]=(short)f2bf(a.z); r[3]=(short)f2bf(a.w);
    r[4]=(short)f2bf(b.x); r[5]=(short)f2bf(b.y); r[6]=(short)f2bf(b.z); r[7]=(short)f2bf(b.w);
    return r;
}

// ---------------- GEMM-NT (unchanged, proven since R2) ----------------
template<int TYPE>
__global__ __launch_bounds__(256)
void gemm_k(const void* __restrict__ Av, const float* __restrict__ W0,
            const float* __restrict__ W1, const float* __restrict__ W2,
            const float* __restrict__ cs, const float* __restrict__ sn,
            unsigned short* __restrict__ qb, unsigned short* __restrict__ kb,
            unsigned short* __restrict__ vtb, float* __restrict__ fout) {
    __shared__ unsigned short As[128*64];
    __shared__ unsigned short Bs[128*64];
    const int tid = threadIdx.x;
    const int w = tid >> 6, lane = tid & 63;
    const int u = lane >> 4, c = lane & 15;
    const int bm = blockIdx.x * 128, bn = blockIdx.y * 128;
    const int wm = (w & 1) * 64, wn = (w >> 1) * 64;
    const int srow = tid >> 3, scol = (tid & 7) << 3;

    const float* Wsec;
    int wrowbase;
    if constexpr (TYPE == 0) {
        const int sec = bn >> 10;
        Wsec = (sec == 0) ? W0 : ((sec == 1) ? W1 : W2);
        wrowbase = bn & 1023;
    } else {
        Wsec = W0;
        wrowbase = bn;
    }
    const float* Wp = Wsec + (size_t)(wrowbase + srow) * K_ + scol;
    const float* Af = (const float*)Av;
    const unsigned short* Ab = (const unsigned short*)Av;

    f32x4 acc[4][4] = {};
    float4 rwf[4][2];
    float4 raf[4][2];
    bf16x8 rab[4];

    auto loadin = [&](int k0) {
        #pragma unroll
        for (int i = 0; i < 4; ++i) {
            if constexpr (TYPE == 0) {
                raf[i][0] = *(const float4*)(Af + (size_t)(bm + srow + i*32) * K_ + scol + k0);
                raf[i][1] = *(const float4*)(Af + (size_t)(bm + srow + i*32) * K_ + scol + k0 + 4);
            } else {
                rab[i] = *(const bf16x8*)(Ab + (size_t)(bm + srow + i*32) * K_ + scol + k0);
            }
            rwf[i][0] = *(const float4*)(Wp + (size_t)i * 32 * K_ + k0);
            rwf[i][1] = *(const float4*)(Wp + (size_t)i * 32 * K_ + k0 + 4);
        }
    };
    loadin(0);

    for (int k0 = 0; k0 < K_; k0 += 64) {
        __syncthreads();
        #pragma unroll
        for (int i = 0; i < 4; ++i) {
            const int row = i * 32 + srow;
            const int sc = (scol * 2) ^ ((row & 7) << 4);
            bf16x8 a8;
            if constexpr (TYPE == 0) a8 = cvt8(raf[i][0], raf[i][1]);
            else                     a8 = rab[i];
            *(bf16x8*)((char*)As + row * 128 + sc) = a8;
            *(bf16x8*)((char*)Bs + row * 128 + sc) = cvt8(rwf[i][0], rwf[i][1]);
        }
        __syncthreads();
        if (k0 < K_ - 64) loadin(k0 + 64);
        #pragma unroll
        for (int kk = 0; kk < 2; ++kk) {
            bf16x8 af[4], bfr[4];
            #pragma unroll
            for (int mi = 0; mi < 4; ++mi) {
                const int row = wm + mi * 16 + c;
                const int sc = (kk * 64 + u * 16) ^ ((row & 7) << 4);
                af[mi] = *(const bf16x8*)((char*)As + row * 128 + sc);
            }
            #pragma unroll
            for (int ni = 0; ni < 4; ++ni) {
                const int row = wn + ni * 16 + c;
                const int sc = (kk * 64 + u * 16) ^ ((row & 7) << 4);
                bfr[ni] = *(const bf16x8*)((char*)Bs + row * 128 + sc);
            }
            #pragma unroll
            for (int mi = 0; mi < 4; ++mi)
                #pragma unroll
                for (int ni = 0; ni < 4; ++ni)
                    acc[mi][ni] = __builtin_amdgcn_mfma_f32_16x16x32_bf16(
                        af[mi], bfr[ni], acc[mi][ni], 0, 0, 0);
        }
    }

    if constexpr (TYPE == 1) {
        #pragma unroll
        for (int mi = 0; mi < 4; ++mi)
            #pragma unroll
            for (int ni = 0; ni < 4; ++ni)
                #pragma unroll
                for (int r = 0; r < 4; ++r)
                    fout[(size_t)(bm + wm + 16*mi + 4*u + r) * HID_ + (bn + wn + 16*ni + c)] =
                        acc[mi][ni][r];
    } else {
        const int sec = bn >> 10;
        const int h = ((bn + wn) & 1023) >> 6;
        if (sec == 2) {
            #pragma unroll
            for (int mi = 0; mi < 4; ++mi)
                #pragma unroll
                for (int r = 0; r < 4; ++r) {
                    const int mg = bm + wm + 16*mi + 4*u + r;
                    const int bb = mg >> 11, t = mg & 2047;
                    #pragma unroll
                    for (int ni = 0; ni < 4; ++ni)
                        vtb[((size_t)(bb*16 + h) * 64 + 16*ni + c) * 2048 + t] =
                            f2bf(acc[mi][ni][r]);
                }
        } else {
            unsigned short* ob = sec ? kb : qb;
            const float qsc = sec ? 1.0f : 0.125f;
            #pragma unroll
            for (int mi = 0; mi < 4; ++mi)
                #pragma unroll
                for (int r = 0; r < 4; ++r) {
                    const int mg = bm + wm + 16*mi + 4*u + r;
                    const int bb = mg >> 11, t = mg & 2047;
                    const size_t base = ((size_t)(bb*16 + h) * 2048 + t) * 64;
                    #pragma unroll
                    for (int ni = 0; ni < 2; ++ni) {
                        const int dlo = 16*ni + c;
                        const float cv = cs[t*64 + dlo], sv = sn[t*64 + dlo];
                        const float Aa = acc[mi][ni][r], Bb = acc[mi][ni+2][r];
                        ob[base + dlo]      = f2bf((Aa*cv - Bb*sv) * qsc);
                        ob[base + dlo + 32] = f2bf((Bb*cv + Aa*sv) * qsc);
                    }
                }
        }
    }
}

// ---------------- 32x32 swapped-MFMA flash attention, 1 wave/block ----------------
// Lane owns q-row (lane&31); halves (lane>=32) hold complementary k/d subsets.
// Cross-half exchange via __shfl_xor(.,32) — unambiguous semantics.
__global__ __launch_bounds__(64)
void attn3(const unsigned short* __restrict__ q, const unsigned short* __restrict__ k,
           const unsigned short* __restrict__ vt, unsigned short* __restrict__ ab) {
    const int lane = threadIdx.x;
    const int h = lane >> 5, c = lane & 31;
    const bool hi = (h != 0);
    const int bh = blockIdx.y, b = bh >> 4, hh = bh & 15;
    const int qblk = (gridDim.x - 1) - blockIdx.x;   // heavy blocks first
    const int q0 = qblk * 32;
    const unsigned short* qp = q  + (size_t)bh * T_ * 64;
    const unsigned short* kp = k  + (size_t)bh * T_ * 64;
    const unsigned short* vp = vt + (size_t)bh * 64 * T_;

    bf16x8 qf[4];
    #pragma unroll
    for (int s = 0; s < 4; ++s)
        qf[s] = *(const bf16x8*)(qp + (size_t)(q0 + c) * 64 + s * 16 + 8 * h);

    f32x16 O0 = {}, O1 = {};
    float m = -1e30f, lsum = 0.f;
    const int nst = qblk + 1;

    auto loadK = [&](bf16x8 (&kf)[4], int st) {
        const int kvs = st << 5;
        #pragma unroll
        for (int s = 0; s < 4; ++s)
            kf[s] = *(const bf16x8*)(kp + (size_t)(kvs + c) * 64 + s * 16 + 8 * h);
    };

    auto process = [&](const bf16x8 (&kf)[4], int st) {
        const int kvs = st << 5;
        // V^T A-fragments (issued first; latency hides under QK^T + softmax)
        bf16x8 vf[4];
        #pragma unroll
        for (int s = 0; s < 4; ++s)
            vf[s] = *(const bf16x8*)(vp + (size_t)(((s >> 1) << 5) + c) * T_
                                        + kvs + ((s & 1) << 4) + 8 * h);
        // S^T = K_tile(32x64) @ Q^T(64x32)
        f32x16 sa = {};
        #pragma unroll
        for (int s = 0; s < 4; ++s)
            sa = __builtin_amdgcn_mfma_f32_32x32x16_bf16(kf[s], qf[s], sa, 0, 0, 0);
        float p[16];
        const bool diag = (st == qblk);
        #pragma unroll
        for (int r = 0; r < 16; ++r) {
            float sv = sa[r];
            if (diag) {
                const int kk = kvs + (r & 3) + 8 * (r >> 2) + 4 * h;
                if (kk > q0 + c) sv = -1e30f;
            }
            p[r] = sv;
        }
        // row max: in-lane tree + one cross-half exchange
        float mx = fmaxf(p[0], p[1]);
        #pragma unroll
        for (int r = 2; r < 16; ++r) mx = fmaxf(mx, p[r]);
        mx = fmaxf(mx, __shfl_xor(mx, 32));
        // defer-max: rescale only when the running max grows materially
        if (!__all(mx <= m + 5.5f)) {
            const float mn = fmaxf(m, mx);
            const float f = __expf(m - mn);
            m = mn;
            lsum *= f;
            #pragma unroll
            for (int r = 0; r < 16; ++r) { O0[r] *= f; O1[r] *= f; }
        }
        float ps = 0.f;
        #pragma unroll
        for (int r = 0; r < 16; ++r) {
            p[r] = __expf(p[r] - m);
            ps += p[r];
        }
        lsum += ps;            // per-half partial; merged once at the end
        // pack to bf16 pairs: o_i holds k-pairs at (r&3)+8*(r>>2)+4h
        unsigned o0 = pk2(p[0], p[1]),   o1 = pk2(p[2], p[3]);
        unsigned o2 = pk2(p[4], p[5]),   o3 = pk2(p[6], p[7]);
        unsigned o4 = pk2(p[8], p[9]),   o5 = pk2(p[10], p[11]);
        unsigned o6 = pk2(p[12], p[13]), o7 = pk2(p[14], p[15]);
        // cross-half partner values
        unsigned x0 = __shfl_xor(o0, 32), x1 = __shfl_xor(o1, 32);
        unsigned x2 = __shfl_xor(o2, 32), x3 = __shfl_xor(o3, 32);
        unsigned x4 = __shfl_xor(o4, 32), x5 = __shfl_xor(o5, 32);
        unsigned x6 = __shfl_xor(o6, 32), x7 = __shfl_xor(o7, 32);
        // B-frag (k = 8h+j within 16-k subtile, col = q = lane&31):
        //  PB0: h0 needs k0..7  = [o0,o1, x0',x1'(partner o0,o1)]; h1 needs k8..15 = [x2,x3, o2,o3]
        //  PB1: same with o4..o7
        u32x4 B0w = { hi ? x2 : o0, hi ? x3 : o1, hi ? o2 : x0, hi ? o3 : x1 };
        u32x4 B1w = { hi ? x6 : o4, hi ? x7 : o5, hi ? o6 : x4, hi ? o7 : x5 };
        bf16x8 PB0 = __builtin_bit_cast(bf16x8, B0w);
        bf16x8 PB1 = __builtin_bit_cast(bf16x8, B1w);
        // O^T += V^T @ P^T
        O0 = __builtin_amdgcn_mfma_f32_32x32x16_bf16(vf[0], PB0, O0, 0, 0, 0);
        O0 = __builtin_amdgcn_mfma_f32_32x32x16_bf16(vf[1], PB1, O0, 0, 0, 0);
        O1 = __builtin_amdgcn_mfma_f32_32x32x16_bf16(vf[2], PB0, O1, 0, 0, 0);
        O1 = __builtin_amdgcn_mfma_f32_32x32x16_bf16(vf[3], PB1, O1, 0, 0, 0);
    };

    bf16x8 kA[4], kB[4];
    loadK(kA, 0);
    for (int st = 0; st < nst; st += 2) {
        const bool hb = (st + 1 < nst);
        if (hb) loadK(kB, st + 1);
        process(kA, st);
        if (!hb) break;
        if (st + 2 < nst) loadK(kA, st + 2);
        process(kB, st + 1);
    }

    // merge the two halves' partial sums, normalize, write q-row (lane-owned)
    lsum += __shfl_xor(lsum, 32);
    const float inv = 1.0f / lsum;
    unsigned short* orow = ab + ((size_t)(b * T_) + q0 + c) * HID_ + hh * 64;
    #pragma unroll
    for (int j = 0; j < 4; ++j) {
        uint2 v0, v1;
        v0.x = pk2(O0[4*j] * inv,     O0[4*j+1] * inv);
        v0.y = pk2(O0[4*j+2] * inv,   O0[4*j+3] * inv);
        v1.x = pk2(O1[4*j] * inv,     O1[4*j+1] * inv);
        v1.y = pk2(O1[4*j+2] * inv,   O1[4*j+3] * inv);
        *(uint2*)(orow + 8*j + 4*h)      = v0;   // d = 8j+4h+{0..3}
        *(uint2*)(orow + 32 + 8*j + 4*h) = v1;   // d = 32+8j+4h+{0..3}
    }
}

extern "C" void kernel_launch(void* const* d_in, const int* in_sizes, int n_in,
                              void* d_out, int out_size, void* d_ws, size_t ws_size,
                              hipStream_t stream) {
    const float* x  = (const float*)d_in[0];
    const float* Wq = (const float*)d_in[1];
    const float* Wk = (const float*)d_in[2];
    const float* Wv = (const float*)d_in[3];
    const float* Wo = (const float*)d_in[4];
    const float* cs = (const float*)d_in[5];
    const float* sn = (const float*)d_in[6];
    char* wsb = (char*)d_ws;
    unsigned short* qb  = (unsigned short*)(wsb);
    unsigned short* kb  = (unsigned short*)(wsb + 8388608);
    unsigned short* vtb = (unsigned short*)(wsb + 16777216);
    unsigned short* ab  = (unsigned short*)(wsb + 25165824);

    gemm_k<0><<<dim3(M_/128, 3072/128), 256, 0, stream>>>(
        x, Wq, Wk, Wv, cs, sn, qb, kb, vtb, nullptr);
    attn3<<<dim3(T_/32, B_*NH_), 64, 0, stream>>>(qb, kb, vtb, ab);
    gemm_k<1><<<dim3(M_/128, HID_/128), 256, 0, stream>>>(
        ab, Wo, nullptr, nullptr, nullptr, nullptr,
        nullptr, nullptr, nullptr, (float*)d_out);
}

// Round 6
// 137.338 us; speedup vs baseline: 13.2021x; 1.3809x over previous
//
#include <hip/hip_runtime.h>
#include <hip/hip_bf16.h>

#define B_   2
#define T_   2048
#define HID_ 1024
#define NH_  16
#define HD_  64
#define K_   1024
#define M_   (B_*T_)

typedef __attribute__((ext_vector_type(8)))  short bf16x8;
typedef __attribute__((ext_vector_type(4)))  float f32x4;
typedef __attribute__((ext_vector_type(16))) float f32x16;
typedef __attribute__((ext_vector_type(4)))  unsigned int u32x4;

__device__ inline unsigned short f2bf(float f) {
    __hip_bfloat16 h = __float2bfloat16(f);
    return __builtin_bit_cast(unsigned short, h);
}
__device__ inline unsigned int pk2(float a, float b) {
    return (unsigned int)f2bf(a) | ((unsigned int)f2bf(b) << 16);
}
__device__ inline bf16x8 cvt8(float4 a, float4 b) {
    bf16x8 r;
    r[0]=(short)f2bf(a.x); r[1]=(short)f2bf(a.y); r[2]=(short)f2bf(a.z); r[3]=(short)f2bf(a.w);
    r[4]=(short)f2bf(b.x); r[5]=(short)f2bf(b.y); r[6]=(short)f2bf(b.z); r[7]=(short)f2bf(b.w);
    return r;
}

// ---------------- GEMM-NT (unchanged, proven since R2) ----------------
template<int TYPE>
__global__ __launch_bounds__(256)
void gemm_k(const void* __restrict__ Av, const float* __restrict__ W0,
            const float* __restrict__ W1, const float* __restrict__ W2,
            const float* __restrict__ cs, const float* __restrict__ sn,
            unsigned short* __restrict__ qb, unsigned short* __restrict__ kb,
            unsigned short* __restrict__ vtb, float* __restrict__ fout) {
    __shared__ unsigned short As[128*64];
    __shared__ unsigned short Bs[128*64];
    const int tid = threadIdx.x;
    const int w = tid >> 6, lane = tid & 63;
    const int u = lane >> 4, c = lane & 15;
    const int bm = blockIdx.x * 128, bn = blockIdx.y * 128;
    const int wm = (w & 1) * 64, wn = (w >> 1) * 64;
    const int srow = tid >> 3, scol = (tid & 7) << 3;

    const float* Wsec;
    int wrowbase;
    if constexpr (TYPE == 0) {
        const int sec = bn >> 10;
        Wsec = (sec == 0) ? W0 : ((sec == 1) ? W1 : W2);
        wrowbase = bn & 1023;
    } else {
        Wsec = W0;
        wrowbase = bn;
    }
    const float* Wp = Wsec + (size_t)(wrowbase + srow) * K_ + scol;
    const float* Af = (const float*)Av;
    const unsigned short* Ab = (const unsigned short*)Av;

    f32x4 acc[4][4] = {};
    float4 rwf[4][2];
    float4 raf[4][2];
    bf16x8 rab[4];

    auto loadin = [&](int k0) {
        #pragma unroll
        for (int i = 0; i < 4; ++i) {
            if constexpr (TYPE == 0) {
                raf[i][0] = *(const float4*)(Af + (size_t)(bm + srow + i*32) * K_ + scol + k0);
                raf[i][1] = *(const float4*)(Af + (size_t)(bm + srow + i*32) * K_ + scol + k0 + 4);
            } else {
                rab[i] = *(const bf16x8*)(Ab + (size_t)(bm + srow + i*32) * K_ + scol + k0);
            }
            rwf[i][0] = *(const float4*)(Wp + (size_t)i * 32 * K_ + k0);
            rwf[i][1] = *(const float4*)(Wp + (size_t)i * 32 * K_ + k0 + 4);
        }
    };
    loadin(0);

    for (int k0 = 0; k0 < K_; k0 += 64) {
        __syncthreads();
        #pragma unroll
        for (int i = 0; i < 4; ++i) {
            const int row = i * 32 + srow;
            const int sc = (scol * 2) ^ ((row & 7) << 4);
            bf16x8 a8;
            if constexpr (TYPE == 0) a8 = cvt8(raf[i][0], raf[i][1]);
            else                     a8 = rab[i];
            *(bf16x8*)((char*)As + row * 128 + sc) = a8;
            *(bf16x8*)((char*)Bs + row * 128 + sc) = cvt8(rwf[i][0], rwf[i][1]);
        }
        __syncthreads();
        if (k0 < K_ - 64) loadin(k0 + 64);
        #pragma unroll
        for (int kk = 0; kk < 2; ++kk) {
            bf16x8 af[4], bfr[4];
            #pragma unroll
            for (int mi = 0; mi < 4; ++mi) {
                const int row = wm + mi * 16 + c;
                const int sc = (kk * 64 + u * 16) ^ ((row & 7) << 4);
                af[mi] = *(const bf16x8*)((char*)As + row * 128 + sc);
            }
            #pragma unroll
            for (int ni = 0; ni < 4; ++ni) {
                const int row = wn + ni * 16 + c;
                const int sc = (kk * 64 + u * 16) ^ ((row & 7) << 4);
                bfr[ni] = *(const bf16x8*)((char*)Bs + row * 128 + sc);
            }
            #pragma unroll
            for (int mi = 0; mi < 4; ++mi)
                #pragma unroll
                for (int ni = 0; ni < 4; ++ni)
                    acc[mi][ni] = __builtin_amdgcn_mfma_f32_16x16x32_bf16(
                        af[mi], bfr[ni], acc[mi][ni], 0, 0, 0);
        }
    }

    if constexpr (TYPE == 1) {
        #pragma unroll
        for (int mi = 0; mi < 4; ++mi)
            #pragma unroll
            for (int ni = 0; ni < 4; ++ni)
                #pragma unroll
                for (int r = 0; r < 4; ++r)
                    fout[(size_t)(bm + wm + 16*mi + 4*u + r) * HID_ + (bn + wn + 16*ni + c)] =
                        acc[mi][ni][r];
    } else {
        const int sec = bn >> 10;
        const int h = ((bn + wn) & 1023) >> 6;
        if (sec == 2) {
            #pragma unroll
            for (int mi = 0; mi < 4; ++mi)
                #pragma unroll
                for (int r = 0; r < 4; ++r) {
                    const int mg = bm + wm + 16*mi + 4*u + r;
                    const int bb = mg >> 11, t = mg & 2047;
                    #pragma unroll
                    for (int ni = 0; ni < 4; ++ni)
                        vtb[((size_t)(bb*16 + h) * 64 + 16*ni + c) * 2048 + t] =
                            f2bf(acc[mi][ni][r]);
                }
        } else {
            unsigned short* ob = sec ? kb : qb;
            const float qsc = sec ? 1.0f : 0.125f;
            #pragma unroll
            for (int mi = 0; mi < 4; ++mi)
                #pragma unroll
                for (int r = 0; r < 4; ++r) {
                    const int mg = bm + wm + 16*mi + 4*u + r;
                    const int bb = mg >> 11, t = mg & 2047;
                    const size_t base = ((size_t)(bb*16 + h) * 2048 + t) * 64;
                    #pragma unroll
                    for (int ni = 0; ni < 2; ++ni) {
                        const int dlo = 16*ni + c;
                        const float cv = cs[t*64 + dlo], sv = sn[t*64 + dlo];
                        const float Aa = acc[mi][ni][r], Bb = acc[mi][ni+2][r];
                        ob[base + dlo]      = f2bf((Aa*cv - Bb*sv) * qsc);
                        ob[base + dlo + 32] = f2bf((Bb*cv + Aa*sv) * qsc);
                    }
                }
        }
    }
}

// ---------------- 32x32 swapped-MFMA flash attention, 4-wave KV-split ----------------
// Block = 4 waves, one (bh, qblk): 32 q rows. Wave w handles KV subtiles w, w+4, ...
// with its own online-softmax partial; partials merged in LDS at the end.
// XCD swizzle: all blocks of a bh land on one XCD (K/V stay in that L2).
__global__ __launch_bounds__(256)
void attn4(const unsigned short* __restrict__ q, const unsigned short* __restrict__ k,
           const unsigned short* __restrict__ vt, unsigned short* __restrict__ ab) {
    const int raw = blockIdx.x;
    const int bh   = (raw & 7) + 8 * ((raw >> 3) & 3);
    const int qblk = 63 - (raw >> 5);                  // heavy blocks first per XCD
    const int tid = threadIdx.x;
    const int wid = tid >> 6, lane = tid & 63;
    const int h = lane >> 5, c = lane & 31;
    const bool hi = (h != 0);
    const int b = bh >> 4, hh = bh & 15;
    const int q0 = qblk * 32;
    const unsigned short* qp = q  + (size_t)bh * T_ * 64;
    const unsigned short* kp = k  + (size_t)bh * T_ * 64;
    const unsigned short* vp = vt + (size_t)bh * 64 * T_;

    bf16x8 qf[4];
    #pragma unroll
    for (int s = 0; s < 4; ++s)
        qf[s] = *(const bf16x8*)(qp + (size_t)(q0 + c) * 64 + s * 16 + 8 * h);

    f32x16 O0 = {}, O1 = {};
    float m = -1e30f, lsum = 0.f;
    const int nst = qblk + 1;

    auto loadKV = [&](bf16x8 (&kf)[4], bf16x8 (&vf)[4], int st) {
        const int kvs = st << 5;
        #pragma unroll
        for (int s = 0; s < 4; ++s)
            kf[s] = *(const bf16x8*)(kp + (size_t)(kvs + c) * 64 + s * 16 + 8 * h);
        #pragma unroll
        for (int s = 0; s < 4; ++s)
            vf[s] = *(const bf16x8*)(vp + (size_t)(((s >> 1) << 5) + c) * T_
                                        + kvs + ((s & 1) << 4) + 8 * h);
    };

    auto process = [&](const bf16x8 (&kf)[4], const bf16x8 (&vf)[4], int st) {
        const int kvs = st << 5;
        f32x16 sa = {};
        #pragma unroll
        for (int s = 0; s < 4; ++s)
            sa = __builtin_amdgcn_mfma_f32_32x32x16_bf16(kf[s], qf[s], sa, 0, 0, 0);
        float p[16];
        const bool diag = (st == qblk);
        #pragma unroll
        for (int r = 0; r < 16; ++r) {
            float sv = sa[r];
            if (diag) {
                const int kk = kvs + (r & 3) + 8 * (r >> 2) + 4 * h;
                if (kk > q0 + c) sv = -1e30f;
            }
            p[r] = sv;
        }
        float mx = fmaxf(p[0], p[1]);
        #pragma unroll
        for (int r = 2; r < 16; ++r) mx = fmaxf(mx, p[r]);
        mx = fmaxf(mx, __shfl_xor(mx, 32));
        if (!__all(mx <= m + 5.5f)) {
            const float mn = fmaxf(m, mx);
            const float f = __expf(m - mn);
            m = mn;
            lsum *= f;
            #pragma unroll
            for (int r = 0; r < 16; ++r) { O0[r] *= f; O1[r] *= f; }
        }
        float ps = 0.f;
        #pragma unroll
        for (int r = 0; r < 16; ++r) {
            p[r] = __expf(p[r] - m);
            ps += p[r];
        }
        lsum += ps;            // per-half partial; merged after the loop
        unsigned o0 = pk2(p[0], p[1]),   o1 = pk2(p[2], p[3]);
        unsigned o2 = pk2(p[4], p[5]),   o3 = pk2(p[6], p[7]);
        unsigned o4 = pk2(p[8], p[9]),   o5 = pk2(p[10], p[11]);
        unsigned o6 = pk2(p[12], p[13]), o7 = pk2(p[14], p[15]);
        unsigned x0 = __shfl_xor(o0, 32), x1 = __shfl_xor(o1, 32);
        unsigned x2 = __shfl_xor(o2, 32), x3 = __shfl_xor(o3, 32);
        unsigned x4 = __shfl_xor(o4, 32), x5 = __shfl_xor(o5, 32);
        unsigned x6 = __shfl_xor(o6, 32), x7 = __shfl_xor(o7, 32);
        u32x4 B0w = { hi ? x2 : o0, hi ? x3 : o1, hi ? o2 : x0, hi ? o3 : x1 };
        u32x4 B1w = { hi ? x6 : o4, hi ? x7 : o5, hi ? o6 : x4, hi ? o7 : x5 };
        bf16x8 PB0 = __builtin_bit_cast(bf16x8, B0w);
        bf16x8 PB1 = __builtin_bit_cast(bf16x8, B1w);
        O0 = __builtin_amdgcn_mfma_f32_32x32x16_bf16(vf[0], PB0, O0, 0, 0, 0);
        O0 = __builtin_amdgcn_mfma_f32_32x32x16_bf16(vf[1], PB1, O0, 0, 0, 0);
        O1 = __builtin_amdgcn_mfma_f32_32x32x16_bf16(vf[2], PB0, O1, 0, 0, 0);
        O1 = __builtin_amdgcn_mfma_f32_32x32x16_bf16(vf[3], PB1, O1, 0, 0, 0);
    };

    bf16x8 kA[4], kB[4], vA[4], vB[4];
    if (wid < nst) loadKV(kA, vA, wid);
    for (int st = wid; st < nst; st += 8) {
        if (st + 4 < nst) loadKV(kB, vB, st + 4);
        process(kA, vA, st);
        if (st + 4 >= nst) break;
        if (st + 8 < nst) loadKV(kA, vA, st + 8);
        process(kB, vB, st + 4);
    }
    lsum += __shfl_xor(lsum, 32);

    // ---- merge the 4 wave-partials in LDS ----
    __shared__ float OS[4][32 * 68];     // per-wave O^T, q-major, padded stride 68
    __shared__ float mS[4][32], lS[4][32];
    if (h == 0) { mS[wid][c] = m; lS[wid][c] = lsum; }
    float* os = &OS[wid][0];
    #pragma unroll
    for (int j = 0; j < 4; ++j) {
        f32x4 t0 = { O0[4*j], O0[4*j+1], O0[4*j+2], O0[4*j+3] };
        f32x4 t1 = { O1[4*j], O1[4*j+1], O1[4*j+2], O1[4*j+3] };
        *(f32x4*)&os[c * 68 + 8*j + 4*h]      = t0;   // d = 8j+4h+{0..3}
        *(f32x4*)&os[c * 68 + 32 + 8*j + 4*h] = t1;   // d = 32+8j+4h+{0..3}
    }
    __syncthreads();

    const int ql = tid & 31, d0 = (tid >> 5) * 8;
    const float M = fmaxf(fmaxf(mS[0][ql], mS[1][ql]), fmaxf(mS[2][ql], mS[3][ql]));
    float acc[8] = {};
    float L = 0.f;
    #pragma unroll
    for (int w = 0; w < 4; ++w) {
        const float sc = __expf(mS[w][ql] - M);
        L += lS[w][ql] * sc;
        f32x4 a = *(f32x4*)&OS[w][ql * 68 + d0];
        f32x4 b2 = *(f32x4*)&OS[w][ql * 68 + d0 + 4];
        #pragma unroll
        for (int t = 0; t < 4; ++t) {
            acc[t]     += a[t]  * sc;
            acc[4 + t] += b2[t] * sc;
        }
    }
    const float inv = 1.0f / L;
    uint4 ov;
    ov.x = pk2(acc[0]*inv, acc[1]*inv);
    ov.y = pk2(acc[2]*inv, acc[3]*inv);
    ov.z = pk2(acc[4]*inv, acc[5]*inv);
    ov.w = pk2(acc[6]*inv, acc[7]*inv);
    *(uint4*)(ab + ((size_t)(b * T_) + q0 + ql) * HID_ + hh * 64 + d0) = ov;
}

extern "C" void kernel_launch(void* const* d_in, const int* in_sizes, int n_in,
                              void* d_out, int out_size, void* d_ws, size_t ws_size,
                              hipStream_t stream) {
    const float* x  = (const float*)d_in[0];
    const float* Wq = (const float*)d_in[1];
    const float* Wk = (const float*)d_in[2];
    const float* Wv = (const float*)d_in[3];
    const float* Wo = (const float*)d_in[4];
    const float* cs = (const float*)d_in[5];
    const float* sn = (const float*)d_in[6];
    char* wsb = (char*)d_ws;
    unsigned short* qb  = (unsigned short*)(wsb);
    unsigned short* kb  = (unsigned short*)(wsb + 8388608);
    unsigned short* vtb = (unsigned short*)(wsb + 16777216);
    unsigned short* ab  = (unsigned short*)(wsb + 25165824);

    gemm_k<0><<<dim3(M_/128, 3072/128), 256, 0, stream>>>(
        x, Wq, Wk, Wv, cs, sn, qb, kb, vtb, nullptr);
    attn4<<<2048, 256, 0, stream>>>(qb, kb, vtb, ab);
    gemm_k<1><<<dim3(M_/128, HID_/128), 256, 0, stream>>>(
        ab, Wo, nullptr, nullptr, nullptr, nullptr,
        nullptr, nullptr, nullptr, (float*)d_out);
}